// Round 2
// baseline (425.323 us; speedup 1.0000x reference)
//
#include <hip/hip_runtime.h>
#include <hip/hip_bf16.h>

// QuantizedLinear: out[64,8192] = x[64,8192] @ (alpha * ternary(W))^T + bias
// R2: LDS-free GEMM. Each lane loads its MFMA B-fragment (8 consecutive fp32
// of one W row) directly from global, ternarizes in-register to bf16 bit
// patterns, and feeds mfma_f32_16x16x32_bf16. A-fragments come directly from
// the bf16 x workspace (L2-resident, 1 MB). No barriers -> no vmcnt(0) gang
// stalls; latency hidden by 16 independent waves/CU + double buffering.

typedef __attribute__((ext_vector_type(8))) short short8;   // 8 bf16 = 4 VGPRs
typedef __attribute__((ext_vector_type(4))) float floatx4;  // MFMA acc

#define B_DIM 64
#define K_DIM 8192
#define O_DIM 8192
#define KSPLIT 8
#define KCHUNK (K_DIM / KSPLIT)   // 1024
#define KSTEPS (KCHUNK / 32)      // 32 MFMA k-blocks per slice

// ---- prep: x fp32 -> bf16 workspace; out = bias broadcast (re-done every call) ----
__global__ __launch_bounds__(256) void prep_kernel(
    const float* __restrict__ x, const float* __restrict__ bias,
    __hip_bfloat16* __restrict__ xbf, float* __restrict__ out) {
  int idx = blockIdx.x * 256 + threadIdx.x;          // 0 .. 524287 (B*K == B*O)
  xbf[idx] = __float2bfloat16(x[idx]);
  out[idx] = bias[idx & (O_DIM - 1)];
}

// ---- main GEMM: 1024 blocks (128 n-tiles x 8 k-slices), 256 thr, no LDS ----
__global__ __launch_bounds__(256, 4) void gemm_kernel(
    const float* __restrict__ w, const unsigned short* __restrict__ xbf,
    const float* __restrict__ alpha, float* __restrict__ out) {
  const int tid = threadIdx.x;
  const int nt  = blockIdx.x & 127;  // n-tile group (fast dim: co-resident blocks share x slice in L2)
  const int ks  = blockIdx.x >> 7;   // k-slice 0..7
  const int wv  = tid >> 6;          // wave 0..3 -> 16-wide n sub-tile
  const int ln  = tid & 63;
  const int llo = ln & 15;           // MFMA frag: n (B) / m (A) / col (C)
  const int lhi = ln >> 4;           // MFMA frag: k quad

  const int nrow  = nt * 64 + wv * 16 + llo;   // W row == output column this lane owns
  const int kbase = ks * KCHUNK + lhi * 8;     // lane's k origin (8 consecutive elems / frag)

  const float* wp = w + (size_t)nrow * K_DIM + kbase;
  const unsigned short* xp = xbf + kbase;
  const float av  = alpha[nrow];
  const float thr = 0.5f * (av + 1e-8f);       // |w| > 0.5*(alpha+eps) -> +/-1

  floatx4 acc[4];
#pragma unroll
  for (int i = 0; i < 4; ++i) acc[i] = (floatx4){0.f, 0.f, 0.f, 0.f};

  float4 wf[2][2];   // raw W frag (8 fp32), double-buffered
  short8 af[2][4];   // x frags for the 4 m sub-tiles, double-buffered

  auto load = [&](int kt, int b) {
    const float* p = wp + kt * 32;
    wf[b][0] = *(const float4*)(p);
    wf[b][1] = *(const float4*)(p + 4);
    const unsigned short* q = xp + kt * 32;
#pragma unroll
    for (int mt = 0; mt < 4; ++mt)
      af[b][mt] = *(const short8*)(const void*)(q + (size_t)(mt * 16 + llo) * K_DIM);
  };

  auto tern = [&](float v) -> short {
    // +1 -> 0x3F80, -1 -> 0xBF80, 0 -> 0 (bf16 bit patterns; 2 cmps + 2 selects)
    return v > thr ? (short)0x3F80
                   : (v < -thr ? (short)(unsigned short)0xBF80 : (short)0);
  };

  auto compute = [&](int b) {
    short8 bf;
    bf[0] = tern(wf[b][0].x); bf[1] = tern(wf[b][0].y);
    bf[2] = tern(wf[b][0].z); bf[3] = tern(wf[b][0].w);
    bf[4] = tern(wf[b][1].x); bf[5] = tern(wf[b][1].y);
    bf[6] = tern(wf[b][1].z); bf[7] = tern(wf[b][1].w);
#pragma unroll
    for (int mt = 0; mt < 4; ++mt)
      acc[mt] = __builtin_amdgcn_mfma_f32_16x16x32_bf16(af[b][mt], bf, acc[mt], 0, 0, 0);
  };

  load(0, 0);
  load(1, 1);
  for (int kt = 0; kt < KSTEPS; kt += 2) {
    compute(0);
    if (kt + 2 < KSTEPS) load(kt + 2, 0);
    compute(1);
    if (kt + 3 < KSTEPS) load(kt + 3, 1);
  }

  // epilogue: C/D col = lane&15 (== nrow's llo), row = lhi*4 + r within m-tile
#pragma unroll
  for (int mt = 0; mt < 4; ++mt) {
    const int m = mt * 16 + lhi * 4;
#pragma unroll
    for (int r = 0; r < 4; ++r) {
      atomicAdd(&out[(size_t)(m + r) * O_DIM + nrow], acc[mt][r] * av);
    }
  }
}

extern "C" void kernel_launch(void* const* d_in, const int* in_sizes, int n_in,
                              void* d_out, int out_size, void* d_ws, size_t ws_size,
                              hipStream_t stream) {
  const float* x     = (const float*)d_in[0];  // [64, 8192]
  const float* w     = (const float*)d_in[1];  // [8192, 8192]
  const float* alpha = (const float*)d_in[2];  // [8192, 1]
  const float* bias  = (const float*)d_in[3];  // [8192]
  float* out = (float*)d_out;                  // [64, 8192]
  __hip_bfloat16* xbf = (__hip_bfloat16*)d_ws; // 1 MB scratch

  prep_kernel<<<(B_DIM * K_DIM) / 256, 256, 0, stream>>>(x, bias, xbf, out);
  gemm_kernel<<<(O_DIM / 64) * KSPLIT, 256, 0, stream>>>(
      w, (const unsigned short*)xbf, alpha, out);
}